// Round 2
// baseline (148.893 us; speedup 1.0000x reference)
//
#include <hip/hip_runtime.h>

// 2-bit quantized embedding gather — per-wave 2-tile software pipeline.
// VOCAB=400000, DIM=128, NBITS=2 -> token t owns 8 aligned int32 words
// bit_arr[8t..8t+7] (32B row); dim d -> word 8t + d/16; 2-bit code;
// out = codebook[code].
//
// History: fused 166.7us (R1) -> ws split 152.5 (R4) -> block LDS 148.7 (R6)
// -> wave-autonomous barrier-free 148.67 (R7, NULL vs R6).
// Counter picture: harness fills = 512MiB @ 6.6 TB/s (80us) dominate the
// timed region; our kernel is <80us (absent from top-5). Mandatory kernel
// traffic = 134MB writes (~20-25us floor) + ~14MB cold reads.
// R8 hypothesis test: R6 and R7 both gave each wave exactly ONE tile ->
// whole-grid phase-lock (all waves gather, then all store). If the kernel
// share is >25us, that's where it hides. This version pipelines 2 tiles
// per wave: issue BOTH gathers up front (async global_load_lds, vmcnt
// in-order), decode tile 0 at vmcnt(1) while tile 1's gather flies, decode
// tile 1 at vmcnt(16) (16 stores max outstanding after the oldest glds).
// If this is a third null, the kernel is at the write roofline and the
// remaining 124us is fixed harness poison cost -> ROOFLINE.

#define TOK_PER_TILE 32
#define TILES_PER_WAVE 2
#define WAVES_PER_BLOCK 4
#define BLOCK 256
#define TOK_PER_WAVE (TOK_PER_TILE * TILES_PER_WAVE)     // 64
#define TOK_PER_BLOCK (TOK_PER_WAVE * WAVES_PER_BLOCK)   // 256

typedef float vfloat4 __attribute__((ext_vector_type(4)));

__global__ __launch_bounds__(BLOCK) void embed2bit_pipe_kernel(
    const int* __restrict__ ids,      // [n_tokens] int32
    const int* __restrict__ bits,     // [3,200,000] packed int32
    const float* __restrict__ cb,     // [4] codebook
    float* __restrict__ out,          // [n_tokens, 128] fp32
    int n_tokens)
{
    // per-wave double buffer: 4 waves x 2 x 1KB = 8 KB
    __shared__ int lds_words[WAVES_PER_BLOCK * 2 * TOK_PER_TILE * 8];

    const int tid  = threadIdx.x;
    const int w    = tid >> 6;
    const int lane = tid & 63;

    const long long wid = (long long)blockIdx.x * WAVES_PER_BLOCK + w;
    const int tb0 = (int)(wid * TOK_PER_WAVE);           // tile 0 first token
    const int tb1 = tb0 + TOK_PER_TILE;                  // tile 1 first token
    if (tb0 >= n_tokens) return;                         // whole-wave exit

    // Clamp indices so BOTH gathers always issue (vmcnt bookkeeping must be
    // exec-independent); out-of-range work is dropped at the store guards.
    const int last = n_tokens - 1;
    int i0 = tb0 + (lane >> 1); if (i0 > last) i0 = last;
    int i1 = tb1 + (lane >> 1); if (i1 > last) i1 = last;

    // Issue both ids loads together (coalesced, one wait before address use).
    int tok0 = ids[i0];
    int tok1 = ids[i1];

    int* b0 = lds_words + (w * 2 + 0) * (TOK_PER_TILE * 8);
    int* b1 = lds_words + (w * 2 + 1) * (TOK_PER_TILE * 8);

    // Async gathers, 16B/lane, lane-ordered LDS dest (m104 contract).
    __builtin_amdgcn_global_load_lds(
        (const __attribute__((address_space(1))) void*)
            (bits + (long long)tok0 * 8 + (lane & 1) * 4),
        (__attribute__((address_space(3))) void*)(b0 + lane * 4), 16, 0, 0);
    __builtin_amdgcn_global_load_lds(
        (const __attribute__((address_space(1))) void*)
            (bits + (long long)tok1 * 8 + (lane & 1) * 4),
        (__attribute__((address_space(3))) void*)(b1 + lane * 4), 16, 0, 0);

    const float c0 = cb[0], c1 = cb[1], c2 = cb[2], c3 = cb[3];

    // ---- Tile 0: wait for the OLDEST gather only; tile 1's stays in flight.
    asm volatile("s_waitcnt vmcnt(1)" ::: "memory");
    __builtin_amdgcn_sched_barrier(0);
    {
        const long long out_base = (long long)tb0 * 128;
        const int rem = n_tokens - tb0;
        const int n_items = (rem >= TOK_PER_TILE ? TOK_PER_TILE : rem) * 32;
#pragma unroll
        for (int q = 0; q < 16; ++q) {
            int item = q * 64 + lane;                 // [0, 1024)
            if (item < n_items) {
                int word = b0[item >> 2];             // 4 lanes broadcast a word
                int byte = (word >> ((item & 3) * 8)) & 0xff;
                vfloat4 r;
#pragma unroll
                for (int j = 0; j < 4; ++j) {
                    int c    = (byte >> (2 * j)) & 3;
                    float lo = (c & 1) ? c1 : c0;
                    float hi = (c & 1) ? c3 : c2;
                    r[j]     = (c & 2) ? hi : lo;
                }
                *reinterpret_cast<vfloat4*>(out + out_base + (long long)item * 4) = r;
            }
        }
    }

    // ---- Tile 1: glds1 is now the OLDEST outstanding vmem; at most 16
    // stores were issued after it. vmcnt(16) => glds1 retired.
    asm volatile("s_waitcnt vmcnt(16)" ::: "memory");
    __builtin_amdgcn_sched_barrier(0);
    {
        const long long out_base = (long long)tb1 * 128;
        const int rem = n_tokens - tb1;
        const int n_items = (rem <= 0 ? 0
                             : (rem >= TOK_PER_TILE ? TOK_PER_TILE : rem)) * 32;
#pragma unroll
        for (int q = 0; q < 16; ++q) {
            int item = q * 64 + lane;
            if (item < n_items) {
                int word = b1[item >> 2];
                int byte = (word >> ((item & 3) * 8)) & 0xff;
                vfloat4 r;
#pragma unroll
                for (int j = 0; j < 4; ++j) {
                    int c    = (byte >> (2 * j)) & 3;
                    float lo = (c & 1) ? c1 : c0;
                    float hi = (c & 1) ? c3 : c2;
                    r[j]     = (c & 2) ? hi : lo;
                }
                *reinterpret_cast<vfloat4*>(out + out_base + (long long)item * 4) = r;
            }
        }
    }
}

extern "C" void kernel_launch(void* const* d_in, const int* in_sizes, int n_in,
                              void* d_out, int out_size, void* d_ws, size_t ws_size,
                              hipStream_t stream) {
    const int*   ids  = (const int*)d_in[0];
    const int*   bits = (const int*)d_in[1];
    const float* cb   = (const float*)d_in[2];
    float*       out  = (float*)d_out;

    int n_tokens = in_sizes[0];                   // 262,144
    int grid = (n_tokens + TOK_PER_BLOCK - 1) / TOK_PER_BLOCK;   // 1024

    embed2bit_pipe_kernel<<<grid, BLOCK, 0, stream>>>(ids, bits, cb, out, n_tokens);
}